// Round 1
// baseline (732.902 us; speedup 1.0000x reference)
//
#include <hip/hip_runtime.h>

// Attn 'general' (Luong) attention: softmax over S of  hidden · (enc @ W^T).
// Key restructure: scores[b,s] = sum_f enc[s,b,f] * v[b,f],  v = hidden @ W.
// Bias term is constant per row -> softmax-invariant -> dropped.
// Roofline: read enc once = 536 MB -> ~85 us @ 6.3 TB/s. Memory-bound.

#define SS 2048
#define BB 64
#define HH 512
#define FF 1024  // 2H

__device__ __forceinline__ void fma4(float4& a, float s, const float4& w) {
    a.x += s * w.x; a.y += s * w.y; a.z += s * w.z; a.w += s * w.w;
}

// ---------------------------------------------------------------------------
// Kernel A: v[b,f] = sum_h hidden[b,h] * W[h,f]
// grid = 32 blocks (2 b-rows each), 256 threads (one float4 column f4=t each).
// W read as float4, coalesced across threads; hidden rows staged in LDS.
// ---------------------------------------------------------------------------
__global__ __launch_bounds__(256) void proj_vec(const float* __restrict__ hidden,
                                                const float* __restrict__ W,
                                                float* __restrict__ v) {
    __shared__ float h0[HH];
    __shared__ float h1[HH];
    const int t  = threadIdx.x;
    const int b0 = blockIdx.x * 2;
    const int b1 = b0 + 1;
    for (int i = t; i < HH; i += 256) {
        h0[i] = hidden[b0 * HH + i];
        h1[i] = hidden[b1 * HH + i];
    }
    __syncthreads();

    const float4* W4 = (const float4*)W;   // [HH][256] float4
    float4 acc0 = {0.f, 0.f, 0.f, 0.f};
    float4 acc1 = {0.f, 0.f, 0.f, 0.f};

    #pragma unroll 4
    for (int h = 0; h < HH; h += 4) {
        float4 ha = *(const float4*)&h0[h];   // broadcast LDS reads (conflict-free)
        float4 hb = *(const float4*)&h1[h];
        float4 w0 = W4[(h + 0) * 256 + t];
        float4 w1 = W4[(h + 1) * 256 + t];
        float4 w2 = W4[(h + 2) * 256 + t];
        float4 w3 = W4[(h + 3) * 256 + t];
        fma4(acc0, ha.x, w0); fma4(acc0, ha.y, w1); fma4(acc0, ha.z, w2); fma4(acc0, ha.w, w3);
        fma4(acc1, hb.x, w0); fma4(acc1, hb.y, w1); fma4(acc1, hb.z, w2); fma4(acc1, hb.w, w3);
    }
    float4* v4 = (float4*)v;
    v4[b0 * 256 + t] = acc0;
    v4[b1 * 256 + t] = acc1;
}

// ---------------------------------------------------------------------------
// Kernel B: scores[b,s] = sum_f enc[s,b,f] * v[b,f]
// One wave per (b, 8 consecutive s). v fragment (16 floats/lane) kept in VGPRs
// and reused across the 8 s -> v traffic hits L2 only. enc loads: float4,
// lane-contiguous (1 KB per instruction per wave). 64-lane shuffle reduce.
// grid = S*B / (4 waves * 8 s) = 4096 blocks.
// ---------------------------------------------------------------------------
#define KS 8
__global__ __launch_bounds__(256) void score_k(const float* __restrict__ enc,
                                               const float* __restrict__ v,
                                               float* __restrict__ scores) {
    const int wave = blockIdx.x * 4 + (threadIdx.x >> 6);
    const int lane = threadIdx.x & 63;
    const int b    = wave & (BB - 1);          // consecutive waves -> adjacent enc rows
    const int s0   = (wave >> 6) * KS;

    const float4* v4 = (const float4*)(v + (size_t)b * FF);
    const float4 v0 = v4[lane +   0];
    const float4 v1 = v4[lane +  64];
    const float4 v2 = v4[lane + 128];
    const float4 v3 = v4[lane + 192];

    #pragma unroll
    for (int k = 0; k < KS; ++k) {
        const int s = s0 + k;
        const float4* e4 = (const float4*)(enc + ((size_t)s * BB + b) * FF);
        float4 e0 = e4[lane +   0];
        float4 e1 = e4[lane +  64];
        float4 e2 = e4[lane + 128];
        float4 e3 = e4[lane + 192];
        float acc = e0.x * v0.x + e0.y * v0.y + e0.z * v0.z + e0.w * v0.w
                  + e1.x * v1.x + e1.y * v1.y + e1.z * v1.z + e1.w * v1.w
                  + e2.x * v2.x + e2.y * v2.y + e2.z * v2.z + e2.w * v2.w
                  + e3.x * v3.x + e3.y * v3.y + e3.z * v3.z + e3.w * v3.w;
        #pragma unroll
        for (int off = 32; off; off >>= 1) acc += __shfl_down(acc, off, 64);
        if (lane == 0) scores[(size_t)b * SS + s] = acc;
    }
}

// ---------------------------------------------------------------------------
// Kernel C: row softmax over S=2048. One block (256 thr) per b; 8 elems/thread.
// ---------------------------------------------------------------------------
__global__ __launch_bounds__(256) void softmax_k(const float* __restrict__ scores,
                                                 float* __restrict__ out) {
    __shared__ float sm[4];
    const int b = blockIdx.x, t = threadIdx.x;
    const int w = t >> 6, lane = t & 63;

    const float4* r4 = (const float4*)(scores + (size_t)b * SS);
    float4 a = r4[t];
    float4 c = r4[t + 256];

    float m = fmaxf(fmaxf(fmaxf(a.x, a.y), fmaxf(a.z, a.w)),
                    fmaxf(fmaxf(c.x, c.y), fmaxf(c.z, c.w)));
    #pragma unroll
    for (int off = 32; off; off >>= 1) m = fmaxf(m, __shfl_down(m, off, 64));
    if (lane == 0) sm[w] = m;
    __syncthreads();
    m = fmaxf(fmaxf(sm[0], sm[1]), fmaxf(sm[2], sm[3]));
    __syncthreads();   // sm reused below

    a.x = __expf(a.x - m); a.y = __expf(a.y - m); a.z = __expf(a.z - m); a.w = __expf(a.w - m);
    c.x = __expf(c.x - m); c.y = __expf(c.y - m); c.z = __expf(c.z - m); c.w = __expf(c.w - m);

    float ssum = a.x + a.y + a.z + a.w + c.x + c.y + c.z + c.w;
    #pragma unroll
    for (int off = 32; off; off >>= 1) ssum += __shfl_down(ssum, off, 64);
    if (lane == 0) sm[w] = ssum;
    __syncthreads();
    const float inv = 1.0f / (sm[0] + sm[1] + sm[2] + sm[3]);

    a.x *= inv; a.y *= inv; a.z *= inv; a.w *= inv;
    c.x *= inv; c.y *= inv; c.z *= inv; c.w *= inv;

    float4* o4 = (float4*)(out + (size_t)b * SS);
    o4[t]       = a;
    o4[t + 256] = c;
}

extern "C" void kernel_launch(void* const* d_in, const int* in_sizes, int n_in,
                              void* d_out, int out_size, void* d_ws, size_t ws_size,
                              hipStream_t stream) {
    const float* hidden = (const float*)d_in[0];   // [1,B,H]
    const float* enc    = (const float*)d_in[1];   // [S,B,2H]
    const float* W      = (const float*)d_in[2];   // [H,2H]
    // d_in[3] = bias: constant per softmax row -> invariant -> unused.
    float* out    = (float*)d_out;                 // [B,1,S]
    float* v      = (float*)d_ws;                  // [B,2H]   = 256 KB
    float* scores = v + BB * FF;                   // [B,S]    = 512 KB

    proj_vec<<<BB / 2, 256, 0, stream>>>(hidden, W, v);
    score_k<<<(SS * BB) / (4 * KS), 256, 0, stream>>>(enc, v, scores);
    softmax_k<<<BB, 256, 0, stream>>>(scores, out);
}

// Round 2
// 672.708 us; speedup vs baseline: 1.0895x; 1.0895x over previous
//
#include <hip/hip_runtime.h>

// Attn 'general' (Luong): out = softmax_s( hidden · (enc @ W^T) ).
// Restructure: scores[b,s] = sum_f enc[s,b,f] * v[b,f],  v = hidden @ W.
// Bias is constant per softmax row -> invariant -> dropped.
// Controllable roofline: read enc once = 536 MB @ ~6.3 TB/s ≈ 85 us.
// (Measured dur_us additionally carries ~600 us of harness reset:
//  2.147 GB ws re-poison fill @337us + 536 MB d_in restore + ~20 small
//  restore dispatches — visible in rocprof, not controllable from here.)

#define SS 2048
#define BB 64
#define HH 512
#define FF 1024  // 2H

typedef float vf4 __attribute__((ext_vector_type(4)));

// ---------------------------------------------------------------------------
// Kernel A: partial projection. grid = 256 blocks = (b, hc), hc splits H into
// 4 chunks of 128. vp[hc][b][f] = sum_{h in chunk} hidden[b,h] * W[h,f].
// 256 blocks -> all work spread across CUs; each block reads only 512 KB of W
// (shared across the 64 b-blocks of the same hc -> L2-hot).
// ---------------------------------------------------------------------------
__global__ __launch_bounds__(256) void proj_partial(const float* __restrict__ hidden,
                                                    const float* __restrict__ W,
                                                    float* __restrict__ vp) {
    __shared__ float hs[128];
    const int t  = threadIdx.x;
    const int b  = blockIdx.x >> 2;
    const int hc = blockIdx.x & 3;
    const int h0 = hc * 128;
    if (t < 128) hs[t] = hidden[b * HH + h0 + t];
    __syncthreads();

    const vf4* W4 = (const vf4*)W;     // [HH][256] float4
    vf4 acc = {0.f, 0.f, 0.f, 0.f};
    #pragma unroll 4
    for (int i = 0; i < 128; ++i) {
        acc += hs[i] * W4[(h0 + i) * 256 + t];
    }
    ((vf4*)vp)[(hc * BB + b) * 256 + t] = acc;
}

// ---------------------------------------------------------------------------
// Kernel B: scores[b,s] = sum_f enc[s,b,f] * v[b,f].
// One wave per (b, 16 consecutive s). v fragment = sum of the 4 hc-partials
// (16 L2-hot float4 loads/lane), then held in VGPRs across all 16 s.
// enc loads: nontemporal float4 (streamed exactly once -> don't pollute L2).
// grid = S*B / (4 waves * 16 s) = 2048 blocks.
// ---------------------------------------------------------------------------
#define KS 16
__global__ __launch_bounds__(256) void score_k(const float* __restrict__ enc,
                                               const float* __restrict__ vp,
                                               float* __restrict__ scores) {
    const int wave = blockIdx.x * 4 + (threadIdx.x >> 6);
    const int lane = threadIdx.x & 63;
    const int b    = wave & (BB - 1);          // adjacent waves -> adjacent enc rows
    const int s0   = (wave >> 6) * KS;

    const vf4* vp4 = (const vf4*)vp;
    vf4 v0 = {0,0,0,0}, v1 = {0,0,0,0}, v2 = {0,0,0,0}, v3 = {0,0,0,0};
    #pragma unroll
    for (int hc = 0; hc < 4; ++hc) {
        const vf4* p = vp4 + (size_t)(hc * BB + b) * 256;
        v0 += p[lane +   0];
        v1 += p[lane +  64];
        v2 += p[lane + 128];
        v3 += p[lane + 192];
    }

    #pragma unroll 4
    for (int k = 0; k < KS; ++k) {
        const int s = s0 + k;
        const vf4* e4 = (const vf4*)(enc + ((size_t)s * BB + b) * FF);
        vf4 e0 = __builtin_nontemporal_load(e4 + lane +   0);
        vf4 e1 = __builtin_nontemporal_load(e4 + lane +  64);
        vf4 e2 = __builtin_nontemporal_load(e4 + lane + 128);
        vf4 e3 = __builtin_nontemporal_load(e4 + lane + 192);
        float acc = e0.x * v0.x + e0.y * v0.y + e0.z * v0.z + e0.w * v0.w
                  + e1.x * v1.x + e1.y * v1.y + e1.z * v1.z + e1.w * v1.w
                  + e2.x * v2.x + e2.y * v2.y + e2.z * v2.z + e2.w * v2.w
                  + e3.x * v3.x + e3.y * v3.y + e3.z * v3.z + e3.w * v3.w;
        #pragma unroll
        for (int off = 32; off; off >>= 1) acc += __shfl_down(acc, off, 64);
        if (lane == 0) scores[(size_t)b * SS + s] = acc;
    }
}

// ---------------------------------------------------------------------------
// Kernel C: row softmax over S=2048. One block (256 thr) per b; 8 elems/thread.
// scores are L2-resident from kernel B -> ~5 us.
// ---------------------------------------------------------------------------
__global__ __launch_bounds__(256) void softmax_k(const float* __restrict__ scores,
                                                 float* __restrict__ out) {
    __shared__ float sm[4];
    const int b = blockIdx.x, t = threadIdx.x;
    const int w = t >> 6, lane = t & 63;

    const vf4* r4 = (const vf4*)(scores + (size_t)b * SS);
    vf4 a = r4[t];
    vf4 c = r4[t + 256];

    float m = fmaxf(fmaxf(fmaxf(a.x, a.y), fmaxf(a.z, a.w)),
                    fmaxf(fmaxf(c.x, c.y), fmaxf(c.z, c.w)));
    #pragma unroll
    for (int off = 32; off; off >>= 1) m = fmaxf(m, __shfl_down(m, off, 64));
    if (lane == 0) sm[w] = m;
    __syncthreads();
    m = fmaxf(fmaxf(sm[0], sm[1]), fmaxf(sm[2], sm[3]));
    __syncthreads();   // sm reused below

    a.x = __expf(a.x - m); a.y = __expf(a.y - m); a.z = __expf(a.z - m); a.w = __expf(a.w - m);
    c.x = __expf(c.x - m); c.y = __expf(c.y - m); c.z = __expf(c.z - m); c.w = __expf(c.w - m);

    float ssum = a.x + a.y + a.z + a.w + c.x + c.y + c.z + c.w;
    #pragma unroll
    for (int off = 32; off; off >>= 1) ssum += __shfl_down(ssum, off, 64);
    if (lane == 0) sm[w] = ssum;
    __syncthreads();
    const float inv = 1.0f / (sm[0] + sm[1] + sm[2] + sm[3]);

    a *= inv;
    c *= inv;

    vf4* o4 = (vf4*)(out + (size_t)b * SS);
    o4[t]       = a;
    o4[t + 256] = c;
}

extern "C" void kernel_launch(void* const* d_in, const int* in_sizes, int n_in,
                              void* d_out, int out_size, void* d_ws, size_t ws_size,
                              hipStream_t stream) {
    const float* hidden = (const float*)d_in[0];   // [1,B,H]
    const float* enc    = (const float*)d_in[1];   // [S,B,2H]
    const float* W      = (const float*)d_in[2];   // [H,2H]
    // d_in[3] = bias: constant per softmax row -> softmax-invariant -> unused.
    float* out    = (float*)d_out;                 // [B,1,S]
    float* vp     = (float*)d_ws;                  // [4][B][2H] partials = 1 MB
    float* scores = vp + 4 * BB * FF;              // [B][S]              = 512 KB

    proj_partial<<<BB * 4, 256, 0, stream>>>(hidden, W, vp);
    score_k<<<(SS / KS) * BB / 4, 256, 0, stream>>>(enc, vp, scores);
    softmax_k<<<BB, 256, 0, stream>>>(scores, out);
}